// Round 6
// baseline (307.800 us; speedup 1.0000x reference)
//
#include <hip/hip_runtime.h>

#define IN_F   128
#define OUTD   64
#define HOUT   256      // H*OUT
#define NEG_SLOPE 0.2f
#define BN_EPS 1e-5f
#define NCOLS  592      // 256 Hh + 256 Hr + 64 res + 8 el/er + 8 zero-pad
#define GEMM_BLOCKS 256
#define K1_THREADS 512
#define K1_WAVES 8

typedef __attribute__((ext_vector_type(8))) short bf16x8;
typedef __attribute__((ext_vector_type(4))) float f32x4;
typedef __attribute__((ext_vector_type(2))) float f32x2;

__device__ __forceinline__ unsigned short f2bf(float f) {
    union { float f; unsigned u; } v; v.f = f;
    unsigned r = (v.u + 0x7FFF + ((v.u >> 16) & 1)) >> 16;   // RNE
    return (unsigned short)r;
}
__device__ __forceinline__ float bf2f(unsigned short h) {
    union { unsigned u; float f; } v; v.u = ((unsigned)h) << 16;
    return v.f;
}

// ============ K0: pack weights -> Btg[592][128] bf16 (k-contig) ============
// cols 0..255 W_fc | 256..511 W_gres | 512..575 W_res | 576..579 wl | 580..583 wr | 584..591 zero
__global__ __launch_bounds__(256) void k0_pack(
    const float* __restrict__ W_fc, const float* __restrict__ W_gres,
    const float* __restrict__ W_res,
    const float* __restrict__ attn_l, const float* __restrict__ attn_r,
    unsigned short* __restrict__ Btg)
{
    int bid = blockIdx.x, t = threadIdx.x;
    if (bid < 288) {
        int idx = bid * 256 + t;          // c*128 + k, c < 576
        int c = idx >> 7, k = idx & 127;
        float v;
        if (c < 256)      v = W_fc[k * HOUT + c];
        else if (c < 512) v = W_gres[k * HOUT + (c - 256)];
        else              v = W_res[k * OUTD + (c - 512)];
        Btg[idx] = f2bf(v);
        return;
    }
    // bid == 288: wl/wr folded attention vectors + zero pad
    for (int p = t; p < 512; p += 256) {
        int h = p >> 7, k = p & 127;
        float sl = 0.f, sr = 0.f;
        for (int d = 0; d < 64; ++d) {
            float wv = W_fc[k * HOUT + h * 64 + d];
            sl += wv * attn_l[h * 64 + d];
            sr += wv * attn_r[h * 64 + d];
        }
        Btg[(576 + h) * 128 + k] = f2bf(sl);
        Btg[(580 + h) * 128 + k] = f2bf(sr);
    }
    for (int idx = t; idx < 8 * 128; idx += 256)
        Btg[584 * 128 + idx] = 0;
}

// ============ K1: B-stationary MFMA GEMM (B in LDS once) + el/er tile + hist tail ============
// outputs: Hh8 fp8 [r][d][head] (256 B/row) ; Hr8 fp8 gat_res+bias ; Rres bf16 [r][d] ;
//          el/er fp32 [r][4] ; rank/degree histogram
__global__ __launch_bounds__(512, 2) void k1_gemm(
    const float* __restrict__ A, const unsigned short* __restrict__ Btg,
    const float* __restrict__ gat_bias, const float* __restrict__ res_b,
    const int* __restrict__ dst, int* __restrict__ degree, int* __restrict__ rank,
    unsigned char* __restrict__ Hh8, unsigned char* __restrict__ Hr8,
    unsigned short* __restrict__ Rres,
    float* __restrict__ el, float* __restrict__ er,
    int N, int E)
{
    __shared__ __align__(16) unsigned short Bsh[NCOLS * 128];   // 151552 B
    int t = threadIdx.x;
    int w = t >> 6, lane = t & 63, quad = lane >> 4, n15 = lane & 15;

    // ---- stage ALL of B into LDS (16B-chunk XOR swizzle: col stride 256B is unpadded) ----
    for (int slot = t; slot < NCOLS * 16; slot += K1_THREADS) {
        int c = slot >> 4, ch = slot & 15;
        uint4 v = *(const uint4*)(Btg + c * 128 + ch * 8);
        *(uint4*)(&Bsh[c * 128 + ((ch ^ (c & 15)) << 3)]) = v;
    }
    __syncthreads();

    // hoisted bias vectors (lane-fixed)
    float gbv[4][4], rbv[4];
#pragma unroll
    for (int hd = 0; hd < 4; ++hd)
#pragma unroll
        for (int j = 0; j < 4; ++j) gbv[hd][j] = gat_bias[hd * 64 + j * 16 + n15];
#pragma unroll
    for (int j = 0; j < 4; ++j) rbv[j] = res_b[j * 16 + n15];

    int chs[4];   // swizzled chunk offsets (shorts) per ks
#pragma unroll
    for (int ks = 0; ks < 4; ++ks) chs[ks] = (((ks << 2) + quad) ^ n15) << 3;

    int gw = blockIdx.x * K1_WAVES + w;            // 0..2047
    int T = (N + 31) / 32;
    for (int task = gw; task < T; task += GEMM_BLOCKS * K1_WAVES) {
        int m0 = task * 32;

        // A fragments: 2 m-frags x 4 ks, fp32 -> bf16 in-register
        bf16x8 af[2][4];
#pragma unroll
        for (int i = 0; i < 2; ++i) {
            int r = m0 + i * 16 + n15;
#pragma unroll
            for (int ks = 0; ks < 4; ++ks) {
                float4 v0 = make_float4(0.f, 0.f, 0.f, 0.f), v1 = v0;
                if (r < N) {
                    const float* ap = A + (size_t)r * IN_F + ks * 32 + quad * 8;
                    v0 = *(const float4*)ap;
                    v1 = *(const float4*)(ap + 4);
                }
                bf16x8 o;
                o[0] = f2bf(v0.x); o[1] = f2bf(v0.y); o[2] = f2bf(v0.z); o[3] = f2bf(v0.w);
                o[4] = f2bf(v1.x); o[5] = f2bf(v1.y); o[6] = f2bf(v1.z); o[7] = f2bf(v1.w);
                af[i][ks] = o;
            }
        }

        unsigned hpack[2][4][4] = {};
        unsigned rpack[2][4][4] = {};

        for (int n = 0; n < 9; ++n) {
            f32x4 acc[2][4] = {};
#pragma unroll
            for (int ks = 0; ks < 4; ++ks) {
                bf16x8 bfr[4];
#pragma unroll
                for (int j = 0; j < 4; ++j) {
                    int col = n * 64 + j * 16 + n15;       // col&15 == n15
                    bfr[j] = *(const bf16x8*)(&Bsh[col * 128 + chs[ks]]);
                }
#pragma unroll
                for (int i = 0; i < 2; ++i)
#pragma unroll
                    for (int j = 0; j < 4; ++j)
                        acc[i][j] = __builtin_amdgcn_mfma_f32_16x16x32_bf16(af[i][ks], bfr[j], acc[i][j], 0, 0, 0);
            }
            if (n < 4) {
#pragma unroll
                for (int i = 0; i < 2; ++i)
#pragma unroll
                    for (int j = 0; j < 4; ++j)
#pragma unroll
                        for (int reg = 0; reg < 4; ++reg) {
                            float v = acc[i][j][reg];
                            unsigned pk = (unsigned)__builtin_amdgcn_cvt_pk_fp8_f32(v, v, 0, false);
                            hpack[i][j][reg] |= (pk & 0xffu) << (8 * n);
                        }
            } else if (n < 8) {
                int hd = n - 4;
#pragma unroll
                for (int i = 0; i < 2; ++i)
#pragma unroll
                    for (int j = 0; j < 4; ++j)
#pragma unroll
                        for (int reg = 0; reg < 4; ++reg) {
                            float v = acc[i][j][reg] + gbv[hd][j];
                            unsigned pk = (unsigned)__builtin_amdgcn_cvt_pk_fp8_f32(v, v, 0, false);
                            rpack[i][j][reg] |= (pk & 0xffu) << (8 * hd);
                        }
            } else {
#pragma unroll
                for (int i = 0; i < 2; ++i)
#pragma unroll
                    for (int reg = 0; reg < 4; ++reg) {
                        int r = m0 + i * 16 + quad * 4 + reg;
                        if (r < N) {
#pragma unroll
                            for (int j = 0; j < 4; ++j)
                                Rres[(size_t)r * OUTD + j * 16 + n15] = f2bf(acc[i][j][reg] + rbv[j]);
                        }
                    }
            }
        }

        // mini el/er tile (cols 576..591: 4 el, 4 er, 8 zero)
        f32x4 acc2[2] = {};
#pragma unroll
        for (int ks = 0; ks < 4; ++ks) {
            int col = 576 + n15;                       // col&15 == n15
            bf16x8 b = *(const bf16x8*)(&Bsh[col * 128 + chs[ks]]);
            acc2[0] = __builtin_amdgcn_mfma_f32_16x16x32_bf16(af[0][ks], b, acc2[0], 0, 0, 0);
            acc2[1] = __builtin_amdgcn_mfma_f32_16x16x32_bf16(af[1][ks], b, acc2[1], 0, 0, 0);
        }
#pragma unroll
        for (int i = 0; i < 2; ++i)
#pragma unroll
            for (int reg = 0; reg < 4; ++reg) {
                int r = m0 + i * 16 + quad * 4 + reg;
                if (r < N && n15 < 8) {
                    float v = acc2[i][reg];
                    if (n15 < 4) el[(size_t)r * 4 + n15] = v;
                    else         er[(size_t)r * 4 + (n15 - 4)] = v;
                }
            }

        // packed fp8 stores (coalesced dwords)
#pragma unroll
        for (int i = 0; i < 2; ++i)
#pragma unroll
            for (int reg = 0; reg < 4; ++reg) {
                int r = m0 + i * 16 + quad * 4 + reg;
                if (r < N) {
#pragma unroll
                    for (int j = 0; j < 4; ++j) {
                        *(unsigned*)(Hh8 + ((size_t)r << 8) + (j * 16 + n15) * 4) = hpack[i][j][reg];
                        *(unsigned*)(Hr8 + ((size_t)r << 8) + (j * 16 + n15) * 4) = rpack[i][j][reg];
                    }
                }
            }
    }

    // ---- histogram tail (overlaps with still-computing waves) ----
    for (int e = gw * 64 + lane; e < E; e += GEMM_BLOCKS * K1_WAVES * 64)
        rank[e] = atomicAdd(degree + dst[e], 1);
}

// ============ hierarchical scan ============
__global__ __launch_bounds__(256) void scanA_kernel(const int* __restrict__ degree,
                                                    int* __restrict__ excl,
                                                    int* __restrict__ blocksum, int N) {
    __shared__ int sm[256];
    int t = threadIdx.x;
    int i = blockIdx.x * 256 + t;
    int d = (i < N) ? degree[i] : 0;
    sm[t] = d; __syncthreads();
    for (int off = 1; off < 256; off <<= 1) {
        int v = (t >= off) ? sm[t - off] : 0;
        __syncthreads();
        sm[t] += v;
        __syncthreads();
    }
    if (i < N) excl[i] = sm[t] - d;
    if (t == 255) blocksum[blockIdx.x] = sm[255];
}

__global__ __launch_bounds__(256) void scanB_kernel(const int* __restrict__ blocksum,
                                                    int* __restrict__ base, int nb) {
    __shared__ int sm[256];
    int t = threadIdx.x;
    int d = (t < nb) ? blocksum[t] : 0;
    sm[t] = d; __syncthreads();
    for (int off = 1; off < 256; off <<= 1) {
        int v = (t >= off) ? sm[t - off] : 0;
        __syncthreads();
        sm[t] += v;
        __syncthreads();
    }
    if (t < nb) base[t] = sm[t] - d;
}

// ============ scatter + edge-score: es_sorted[p] = {u*256, s01, s23, 0} ============
__global__ void scatter_kernel(const int* __restrict__ src, const int* __restrict__ dst,
                               const int* __restrict__ rank, const int* __restrict__ excl,
                               const int* __restrict__ base,
                               const float* __restrict__ el, const float* __restrict__ er,
                               uint4* __restrict__ es_sorted, int E) {
    int e = blockIdx.x * 256 + threadIdx.x;
    if (e >= E) return;
    int d = dst[e], u = src[e];
    int p = excl[d] + base[d >> 8] + rank[e];
    float4 l = *(const float4*)(el + (size_t)u * 4);
    float4 r = *(const float4*)(er + (size_t)d * 4);
    float x, s0, s1, s2, s3;
    x = l.x + r.x; x = x > 0.f ? x : NEG_SLOPE * x; s0 = __expf(x);
    x = l.y + r.y; x = x > 0.f ? x : NEG_SLOPE * x; s1 = __expf(x);
    x = l.z + r.z; x = x > 0.f ? x : NEG_SLOPE * x; s2 = __expf(x);
    x = l.w + r.w; x = x > 0.f ? x : NEG_SLOPE * x; s3 = __expf(x);
    uint4 o;
    o.x = (unsigned)u << 8;   // pre-scaled byte offset into Hh8
    o.y = (unsigned)f2bf(s0) | ((unsigned)f2bf(s1) << 16);
    o.z = (unsigned)f2bf(s2) | ((unsigned)f2bf(s3) << 16);
    o.w = 0u;
    es_sorted[p] = o;
}

// ============ aggregation + epilogue: readlane broadcast, zero DS-pipe inner loop ============
__global__ __launch_bounds__(256) void agg_kernel(
    const unsigned char* __restrict__ Hh8, const unsigned char* __restrict__ Hr8,
    const unsigned short* __restrict__ Rres,
    const int* __restrict__ excl, const int* __restrict__ base,
    const uint4* __restrict__ es_sorted,
    const float* __restrict__ conv_w, const float* __restrict__ conv_b,
    float* __restrict__ y, int N, int E)
{
    int wave = threadIdx.x >> 6, lane = threadIdx.x & 63;
    int v = blockIdx.x * 4 + wave;
    if (v >= N) return;
    int b  = excl[v] + base[v >> 8];
    int e2 = (v + 1 < N) ? (excl[v + 1] + base[(v + 1) >> 8]) : E;
    int deg = e2 - b;

    const unsigned char* hbase = Hh8 + lane * 4;
    float a0 = 0.f, a1 = 0.f, a2 = 0.f, a3 = 0.f;
    float p0 = 0.f, p1 = 0.f, p2 = 0.f, p3 = 0.f;

    for (int i0 = 0; i0 < deg; i0 += 64) {
        int j = i0 + lane;
        uint4 es = make_uint4(0u, 0u, 0u, 0u);
        if (j < deg) es = es_sorted[b + j];
        p0 += bf2f((unsigned short)(es.y & 0xffff));
        p1 += bf2f((unsigned short)(es.y >> 16));
        p2 += bf2f((unsigned short)(es.z & 0xffff));
        p3 += bf2f((unsigned short)(es.z >> 16));
        int cl = deg - i0; if (cl > 64) cl = 64;
        int jj = 0;
        for (; jj + 1 < cl; jj += 2) {
            unsigned uA   = (unsigned)__builtin_amdgcn_readlane((int)es.x, jj);
            unsigned sA01 = (unsigned)__builtin_amdgcn_readlane((int)es.y, jj);
            unsigned sA23 = (unsigned)__builtin_amdgcn_readlane((int)es.z, jj);
            unsigned uB   = (unsigned)__builtin_amdgcn_readlane((int)es.x, jj + 1);
            unsigned sB01 = (unsigned)__builtin_amdgcn_readlane((int)es.y, jj + 1);
            unsigned sB23 = (unsigned)__builtin_amdgcn_readlane((int)es.z, jj + 1);
            unsigned hvA = *(const unsigned*)(hbase + uA);
            unsigned hvB = *(const unsigned*)(hbase + uB);
            f32x2 loA = __builtin_amdgcn_cvt_pk_f32_fp8(hvA, false);
            f32x2 hiA = __builtin_amdgcn_cvt_pk_f32_fp8(hvA, true);
            f32x2 loB = __builtin_amdgcn_cvt_pk_f32_fp8(hvB, false);
            f32x2 hiB = __builtin_amdgcn_cvt_pk_f32_fp8(hvB, true);
            a0 += bf2f((unsigned short)(sA01 & 0xffff)) * loA.x;
            a1 += bf2f((unsigned short)(sA01 >> 16))    * loA.y;
            a2 += bf2f((unsigned short)(sA23 & 0xffff)) * hiA.x;
            a3 += bf2f((unsigned short)(sA23 >> 16))    * hiA.y;
            a0 += bf2f((unsigned short)(sB01 & 0xffff)) * loB.x;
            a1 += bf2f((unsigned short)(sB01 >> 16))    * loB.y;
            a2 += bf2f((unsigned short)(sB23 & 0xffff)) * hiB.x;
            a3 += bf2f((unsigned short)(sB23 >> 16))    * hiB.y;
        }
        if (jj < cl) {
            unsigned uA   = (unsigned)__builtin_amdgcn_readlane((int)es.x, jj);
            unsigned sA01 = (unsigned)__builtin_amdgcn_readlane((int)es.y, jj);
            unsigned sA23 = (unsigned)__builtin_amdgcn_readlane((int)es.z, jj);
            unsigned hvA = *(const unsigned*)(hbase + uA);
            f32x2 loA = __builtin_amdgcn_cvt_pk_f32_fp8(hvA, false);
            f32x2 hiA = __builtin_amdgcn_cvt_pk_f32_fp8(hvA, true);
            a0 += bf2f((unsigned short)(sA01 & 0xffff)) * loA.x;
            a1 += bf2f((unsigned short)(sA01 >> 16))    * loA.y;
            a2 += bf2f((unsigned short)(sA23 & 0xffff)) * hiA.x;
            a3 += bf2f((unsigned short)(sA23 >> 16))    * hiA.y;
        }
    }
#pragma unroll
    for (int off = 1; off < 64; off <<= 1) {
        p0 += __shfl_xor(p0, off); p1 += __shfl_xor(p1, off);
        p2 += __shfl_xor(p2, off); p3 += __shfl_xor(p3, off);
    }
    float r0 = 1.f / (p0 + 1e-16f), r1 = 1.f / (p1 + 1e-16f);
    float r2 = 1.f / (p2 + 1e-16f), r3 = 1.f / (p3 + 1e-16f);

    unsigned hr = *(const unsigned*)(Hr8 + ((size_t)v << 8) + lane * 4);
    f32x2 rlo = __builtin_amdgcn_cvt_pk_f32_fp8(hr, false);
    f32x2 rhi = __builtin_amdgcn_cvt_pk_f32_fp8(hr, true);
    float resv = bf2f(Rres[(size_t)v * OUTD + lane]);
    float yv = conv_b[0] + (resv > 0.f ? resv : 0.f);
    float tt;
    tt = a0 * r0 + rlo.x; tt = tt > 0.f ? tt : 0.f; yv += conv_w[0] * tt;
    tt = a1 * r1 + rlo.y; tt = tt > 0.f ? tt : 0.f; yv += conv_w[1] * tt;
    tt = a2 * r2 + rhi.x; tt = tt > 0.f ? tt : 0.f; yv += conv_w[2] * tt;
    tt = a3 * r3 + rhi.y; tt = tt > 0.f ? tt : 0.f; yv += conv_w[3] * tt;
    y[(size_t)v * OUTD + lane] = yv;
}

// ============ BN tail ============
__global__ __launch_bounds__(256) void bn_partial_kernel(const float* __restrict__ y,
                                                         float* __restrict__ bnsum,
                                                         float* __restrict__ bnsumsq, int total) {
    __shared__ float smem[256];
    int t = threadIdx.x;
    size_t idx = (size_t)blockIdx.x * 256 + t;
    size_t stride = (size_t)gridDim.x * 256;
    float sum = 0.f, sq = 0.f;
    for (; idx < (size_t)total; idx += stride) {
        float v = y[idx];
        sum += v; sq += v * v;
    }
    int d = t & 63;
    smem[t] = sum; __syncthreads();
    if (t < 64) atomicAdd(bnsum + d, smem[t] + smem[t + 64] + smem[t + 128] + smem[t + 192]);
    __syncthreads();
    smem[t] = sq; __syncthreads();
    if (t < 64) atomicAdd(bnsumsq + d, smem[t] + smem[t + 64] + smem[t + 128] + smem[t + 192]);
}

__global__ void norm_kernel(const float* __restrict__ y,
                            const float* __restrict__ bnsum, const float* __restrict__ bnsumsq,
                            const float* __restrict__ gamma, const float* __restrict__ beta,
                            float* __restrict__ out, int total4, float invN) {
    int idx = blockIdx.x * blockDim.x + threadIdx.x;
    if (idx >= total4) return;
    float4 v = *(const float4*)(y + (size_t)idx * 4);
    int d = (idx * 4) & 63;
    float4 o;
#pragma unroll
    for (int k = 0; k < 4; ++k) {
        float mean = bnsum[d + k] * invN;
        float var = bnsumsq[d + k] * invN - mean * mean;
        float sc = gamma[d + k] * rsqrtf(var + BN_EPS);
        float sh = beta[d + k] - mean * sc;
        (&o.x)[k] = (&v.x)[k] * sc + sh;
    }
    *(float4*)(out + (size_t)idx * 4) = o;
}

// ============ launch ============
extern "C" void kernel_launch(void* const* d_in, const int* in_sizes, int n_in,
                              void* d_out, int out_size, void* d_ws, size_t ws_size,
                              hipStream_t stream) {
    const float* node_feats = (const float*)d_in[0];
    const float* W_fc       = (const float*)d_in[1];
    const float* attn_l     = (const float*)d_in[2];
    const float* attn_r     = (const float*)d_in[3];
    const float* gat_res_w  = (const float*)d_in[4];
    const float* gat_bias   = (const float*)d_in[5];
    const float* conv_w     = (const float*)d_in[6];
    const float* conv_b     = (const float*)d_in[7];
    const float* res_w      = (const float*)d_in[8];
    const float* res_b      = (const float*)d_in[9];
    const float* bn_gamma   = (const float*)d_in[10];
    const float* bn_beta    = (const float*)d_in[11];
    const int*   src        = (const int*)d_in[12];
    const int*   dst        = (const int*)d_in[13];

    const int N = in_sizes[0] / IN_F;
    const int E = in_sizes[12];
    const int nb = (N + 255) / 256;

    char* ws = (char*)d_ws;
    size_t off = 0;
    auto alloc = [&](size_t bytes) -> void* {
        void* p = (void*)(ws + off);
        off += (bytes + 255) & ~(size_t)255;
        return p;
    };

    // --- zero zone ---
    int*   degree  = (int*)alloc((size_t)N * 4);
    float* bnsum   = (float*)alloc(64 * 4);
    float* bnsumsq = (float*)alloc(64 * 4);
    size_t zero_bytes = off;
    // --- rest ---
    int*            rank      = (int*)alloc((size_t)E * 4);
    int*            excl      = (int*)alloc((size_t)N * 4);
    int*            blocksum  = (int*)alloc(256 * 4);
    int*            base      = (int*)alloc(256 * 4);
    uint4*          es_sorted = (uint4*)alloc((size_t)E * 16);
    unsigned short* Btg       = (unsigned short*)alloc((size_t)NCOLS * IN_F * 2);
    unsigned char*  Hh8       = (unsigned char*)alloc((size_t)N * 256);
    unsigned char*  Hr8       = (unsigned char*)alloc((size_t)N * 256);
    unsigned short* Rres      = (unsigned short*)alloc((size_t)N * OUTD * 2);
    float*          el        = (float*)alloc((size_t)N * 4 * 4);
    float*          er        = (float*)alloc((size_t)N * 4 * 4);
    float*          y         = (float*)alloc((size_t)N * OUTD * 4);
    (void)ws_size; (void)n_in; (void)out_size;

    hipMemsetAsync(d_ws, 0, zero_bytes, stream);

    // 0. pack B weights (+ folded attention vectors)
    k0_pack<<<289, 256, 0, stream>>>(W_fc, gat_res_w, res_w, attn_l, attn_r, Btg);
    // 1. B-stationary MFMA GEMM + el/er + histogram tail
    k1_gemm<<<GEMM_BLOCKS, K1_THREADS, 0, stream>>>(node_feats, Btg, gat_bias, res_b,
                                                    dst, degree, rank, Hh8, Hr8, Rres,
                                                    el, er, N, E);
    // 2. scan
    scanA_kernel<<<nb, 256, 0, stream>>>(degree, excl, blocksum, N);
    scanB_kernel<<<1, 256, 0, stream>>>(blocksum, base, nb);
    // 3. scatter + score compute
    scatter_kernel<<<(E + 255) / 256, 256, 0, stream>>>(src, dst, rank, excl, base,
                                                        el, er, es_sorted, E);
    // 4. aggregation + epilogue
    agg_kernel<<<(N + 3) / 4, 256, 0, stream>>>(Hh8, Hr8, Rres, excl, base, es_sorted,
                                                conv_w, conv_b, y, N, E);
    // 5. BN
    bn_partial_kernel<<<512, 256, 0, stream>>>(y, bnsum, bnsumsq, N * OUTD);
    norm_kernel<<<(N * OUTD / 4 + 255) / 256, 256, 0, stream>>>(y, bnsum, bnsumsq,
                                                                bn_gamma, bn_beta, (float*)d_out,
                                                                N * OUTD / 4, 1.f / (float)N);
}

// Round 7
// 258.737 us; speedup vs baseline: 1.1896x; 1.1896x over previous
//
#include <hip/hip_runtime.h>

#define IN_F   128
#define OUTD   64
#define HOUT   256      // H*OUT
#define NEG_SLOPE 0.2f
#define BN_EPS 1e-5f
#define NCOLS  592      // 256 Hh + 256 Hr + 64 res + 8 el/er + 8 zero-pad
#define K1_BLOCKS 512   // 2 blocks/CU exactly; 2048 waves
#define K1_TOTWAVES (K1_BLOCKS * 4)

typedef __attribute__((ext_vector_type(8))) short bf16x8;
typedef __attribute__((ext_vector_type(4))) float f32x4;
typedef __attribute__((ext_vector_type(2))) float f32x2;

__device__ __forceinline__ unsigned short f2bf(float f) {
    union { float f; unsigned u; } v; v.f = f;
    unsigned r = (v.u + 0x7FFF + ((v.u >> 16) & 1)) >> 16;   // RNE
    return (unsigned short)r;
}
__device__ __forceinline__ float bf2f(unsigned short h) {
    union { unsigned u; float f; } v; v.u = ((unsigned)h) << 16;
    return v.f;
}

// fragment-order index for Btg2: col c (0..591), k (0..127) ->
// (((n*4+j)*4+ks)*64 + quad*16 + n15)*8 + kk   [bf16 units]
__device__ __forceinline__ int b2idx(int c, int k) {
    int n = c >> 6, j = (c >> 4) & 3, n15 = c & 15;
    int ks = k >> 5, qd = (k >> 3) & 3, kk = k & 7;
    return ((((n * 4 + j) * 4 + ks) * 64) + qd * 16 + n15) * 8 + kk;
}

// ============ K0: pack weights -> Btg2 (fragment-ordered bf16) ============
// cols 0..255 W_fc | 256..511 W_gres | 512..575 W_res | 576..579 wl | 580..583 wr | 584..591 zero
__global__ __launch_bounds__(256) void k0_pack(
    const float* __restrict__ W_fc, const float* __restrict__ W_gres,
    const float* __restrict__ W_res,
    const float* __restrict__ attn_l, const float* __restrict__ attn_r,
    unsigned short* __restrict__ Btg2)
{
    int bid = blockIdx.x, t = threadIdx.x;
    if (bid < 288) {
        int idx = bid * 256 + t;          // c*128 + k, c < 576
        int c = idx >> 7, k = idx & 127;
        float v;
        if (c < 256)      v = W_fc[k * HOUT + c];
        else if (c < 512) v = W_gres[k * HOUT + (c - 256)];
        else              v = W_res[k * OUTD + (c - 512)];
        Btg2[b2idx(c, k)] = f2bf(v);
        return;
    }
    // bid == 288: wl/wr folded attention vectors + zero pad
    for (int p = t; p < 512; p += 256) {
        int h = p >> 7, k = p & 127;
        float sl = 0.f, sr = 0.f;
        for (int d = 0; d < 64; ++d) {
            float wv = W_fc[k * HOUT + h * 64 + d];
            sl += wv * attn_l[h * 64 + d];
            sr += wv * attn_r[h * 64 + d];
        }
        Btg2[b2idx(576 + h, k)] = f2bf(sl);
        Btg2[b2idx(580 + h, k)] = f2bf(sr);
    }
    for (int p = t; p < 8 * 128; p += 256) {
        int c = 584 + (p >> 7), k = p & 127;
        Btg2[b2idx(c, k)] = 0;
    }
}

// ============ K1: LDS-free barrier-free MFMA GEMM, one wave per 32-row task ============
// B fragments: coalesced 1KB wave loads from L2-resident Btg2. A: global 128B segments.
// outputs: Hh8 fp8 [r][d][head] ; Hr8 fp8 gat_res+bias ; Rres bf16 [r][d] ; el/er fp32 [r][4]
__global__ __launch_bounds__(256) void k1_gemm(
    const float* __restrict__ A, const unsigned short* __restrict__ Btg2,
    const float* __restrict__ gat_bias, const float* __restrict__ res_b,
    const int* __restrict__ dst, int* __restrict__ degree, int* __restrict__ rank,
    unsigned char* __restrict__ Hh8, unsigned char* __restrict__ Hr8,
    unsigned short* __restrict__ Rres,
    float* __restrict__ el, float* __restrict__ er,
    int N, int E)
{
    int t = threadIdx.x;
    int w = t >> 6, lane = t & 63, quad = lane >> 4, n15 = lane & 15;
    int gw = blockIdx.x * 4 + w;              // 0..2047
    int T = (N + 31) / 32;

    if (gw < T) {
        int m0 = gw * 32;

        // A fragments: 2 m-frags x 4 ks, fp32 -> bf16 in-register
        bf16x8 af[2][4];
#pragma unroll
        for (int i = 0; i < 2; ++i) {
            int r = m0 + i * 16 + n15;
#pragma unroll
            for (int ks = 0; ks < 4; ++ks) {
                float4 v0 = make_float4(0.f, 0.f, 0.f, 0.f), v1 = v0;
                if (r < N) {
                    const float* ap = A + (size_t)r * IN_F + ks * 32 + quad * 8;
                    v0 = *(const float4*)ap;
                    v1 = *(const float4*)(ap + 4);
                }
                bf16x8 o;
                o[0] = f2bf(v0.x); o[1] = f2bf(v0.y); o[2] = f2bf(v0.z); o[3] = f2bf(v0.w);
                o[4] = f2bf(v1.x); o[5] = f2bf(v1.y); o[6] = f2bf(v1.z); o[7] = f2bf(v1.w);
                af[i][ks] = o;
            }
        }

        // hoisted bias vectors (lane-fixed)
        float gbv[4][4], rbv[4];
#pragma unroll
        for (int hd = 0; hd < 4; ++hd)
#pragma unroll
            for (int j = 0; j < 4; ++j) gbv[hd][j] = gat_bias[hd * 64 + j * 16 + n15];
#pragma unroll
        for (int j = 0; j < 4; ++j) rbv[j] = res_b[j * 16 + n15];

        unsigned hpack[2][4][4] = {};
        unsigned rpack[2][4][4] = {};
        int lofs = (quad * 16 + n15) * 8;     // lane's slot within a 1KB fragment block

        for (int n = 0; n < 9; ++n) {
            f32x4 acc[2][4] = {};
#pragma unroll
            for (int ks = 0; ks < 4; ++ks) {
                bf16x8 bfr[4];
#pragma unroll
                for (int j = 0; j < 4; ++j)
                    bfr[j] = *(const bf16x8*)(Btg2 + (((n * 4 + j) * 4 + ks) << 9) + lofs);
#pragma unroll
                for (int i = 0; i < 2; ++i)
#pragma unroll
                    for (int j = 0; j < 4; ++j)
                        acc[i][j] = __builtin_amdgcn_mfma_f32_16x16x32_bf16(af[i][ks], bfr[j], acc[i][j], 0, 0, 0);
            }
            if (n < 4) {
#pragma unroll
                for (int i = 0; i < 2; ++i)
#pragma unroll
                    for (int j = 0; j < 4; ++j)
#pragma unroll
                        for (int reg = 0; reg < 4; ++reg) {
                            float v = acc[i][j][reg];
                            unsigned pk = (unsigned)__builtin_amdgcn_cvt_pk_fp8_f32(v, v, 0, false);
                            hpack[i][j][reg] |= (pk & 0xffu) << (8 * n);
                        }
            } else if (n < 8) {
                int hd = n - 4;
#pragma unroll
                for (int i = 0; i < 2; ++i)
#pragma unroll
                    for (int j = 0; j < 4; ++j)
#pragma unroll
                        for (int reg = 0; reg < 4; ++reg) {
                            float v = acc[i][j][reg] + gbv[hd][j];
                            unsigned pk = (unsigned)__builtin_amdgcn_cvt_pk_fp8_f32(v, v, 0, false);
                            rpack[i][j][reg] |= (pk & 0xffu) << (8 * hd);
                        }
            } else {
#pragma unroll
                for (int i = 0; i < 2; ++i)
#pragma unroll
                    for (int reg = 0; reg < 4; ++reg) {
                        int r = m0 + i * 16 + quad * 4 + reg;
                        if (r < N) {
#pragma unroll
                            for (int j = 0; j < 4; ++j)
                                Rres[(size_t)r * OUTD + j * 16 + n15] = f2bf(acc[i][j][reg] + rbv[j]);
                        }
                    }
            }
        }

        // mini el/er tile (n=9, j=0: cols 576..591 -> 4 el, 4 er, 8 zero)
        f32x4 acc2[2] = {};
#pragma unroll
        for (int ks = 0; ks < 4; ++ks) {
            bf16x8 b = *(const bf16x8*)(Btg2 + (((9 * 4 + 0) * 4 + ks) << 9) + lofs);
            acc2[0] = __builtin_amdgcn_mfma_f32_16x16x32_bf16(af[0][ks], b, acc2[0], 0, 0, 0);
            acc2[1] = __builtin_amdgcn_mfma_f32_16x16x32_bf16(af[1][ks], b, acc2[1], 0, 0, 0);
        }
#pragma unroll
        for (int i = 0; i < 2; ++i)
#pragma unroll
            for (int reg = 0; reg < 4; ++reg) {
                int r = m0 + i * 16 + quad * 4 + reg;
                if (r < N && n15 < 8) {
                    float v = acc2[i][reg];
                    if (n15 < 4) el[(size_t)r * 4 + n15] = v;
                    else         er[(size_t)r * 4 + (n15 - 4)] = v;
                }
            }

        // packed fp8 stores (4 rows x 64B aligned segments per inst)
#pragma unroll
        for (int i = 0; i < 2; ++i)
#pragma unroll
            for (int reg = 0; reg < 4; ++reg) {
                int r = m0 + i * 16 + quad * 4 + reg;
                if (r < N) {
#pragma unroll
                    for (int j = 0; j < 4; ++j) {
                        *(unsigned*)(Hh8 + ((size_t)r << 8) + (j * 16 + n15) * 4) = hpack[i][j][reg];
                        *(unsigned*)(Hr8 + ((size_t)r << 8) + (j * 16 + n15) * 4) = rpack[i][j][reg];
                    }
                }
            }
    }

    // ---- histogram (all 2048 waves participate; overlaps GEMM waves) ----
    for (int e = gw * 64 + lane; e < E; e += K1_TOTWAVES * 64)
        rank[e] = atomicAdd(degree + dst[e], 1);
}

// ============ hierarchical scan ============
__global__ __launch_bounds__(256) void scanA_kernel(const int* __restrict__ degree,
                                                    int* __restrict__ excl,
                                                    int* __restrict__ blocksum, int N) {
    __shared__ int sm[256];
    int t = threadIdx.x;
    int i = blockIdx.x * 256 + t;
    int d = (i < N) ? degree[i] : 0;
    sm[t] = d; __syncthreads();
    for (int off = 1; off < 256; off <<= 1) {
        int v = (t >= off) ? sm[t - off] : 0;
        __syncthreads();
        sm[t] += v;
        __syncthreads();
    }
    if (i < N) excl[i] = sm[t] - d;
    if (t == 255) blocksum[blockIdx.x] = sm[255];
}

__global__ __launch_bounds__(256) void scanB_kernel(const int* __restrict__ blocksum,
                                                    int* __restrict__ base, int nb) {
    __shared__ int sm[256];
    int t = threadIdx.x;
    int d = (t < nb) ? blocksum[t] : 0;
    sm[t] = d; __syncthreads();
    for (int off = 1; off < 256; off <<= 1) {
        int v = (t >= off) ? sm[t - off] : 0;
        __syncthreads();
        sm[t] += v;
        __syncthreads();
    }
    if (t < nb) base[t] = sm[t] - d;
}

// ============ scatter + edge-score: es_sorted[p] = {u*256, s01, s23, 0} ============
__global__ void scatter_kernel(const int* __restrict__ src, const int* __restrict__ dst,
                               const int* __restrict__ rank, const int* __restrict__ excl,
                               const int* __restrict__ base,
                               const float* __restrict__ el, const float* __restrict__ er,
                               uint4* __restrict__ es_sorted, int E) {
    int e = blockIdx.x * 256 + threadIdx.x;
    if (e >= E) return;
    int d = dst[e], u = src[e];
    int p = excl[d] + base[d >> 8] + rank[e];
    float4 l = *(const float4*)(el + (size_t)u * 4);
    float4 r = *(const float4*)(er + (size_t)d * 4);
    float x, s0, s1, s2, s3;
    x = l.x + r.x; x = x > 0.f ? x : NEG_SLOPE * x; s0 = __expf(x);
    x = l.y + r.y; x = x > 0.f ? x : NEG_SLOPE * x; s1 = __expf(x);
    x = l.z + r.z; x = x > 0.f ? x : NEG_SLOPE * x; s2 = __expf(x);
    x = l.w + r.w; x = x > 0.f ? x : NEG_SLOPE * x; s3 = __expf(x);
    uint4 o;
    o.x = (unsigned)u << 8;   // pre-scaled byte offset into Hh8
    o.y = (unsigned)f2bf(s0) | ((unsigned)f2bf(s1) << 16);
    o.z = (unsigned)f2bf(s2) | ((unsigned)f2bf(s3) << 16);
    o.w = 0u;
    es_sorted[p] = o;
}

// ============ aggregation + epilogue: readlane broadcast, zero DS-pipe inner loop ============
__global__ __launch_bounds__(256) void agg_kernel(
    const unsigned char* __restrict__ Hh8, const unsigned char* __restrict__ Hr8,
    const unsigned short* __restrict__ Rres,
    const int* __restrict__ excl, const int* __restrict__ base,
    const uint4* __restrict__ es_sorted,
    const float* __restrict__ conv_w, const float* __restrict__ conv_b,
    float* __restrict__ y, int N, int E)
{
    int wave = threadIdx.x >> 6, lane = threadIdx.x & 63;
    int v = blockIdx.x * 4 + wave;
    if (v >= N) return;
    int b  = excl[v] + base[v >> 8];
    int e2 = (v + 1 < N) ? (excl[v + 1] + base[(v + 1) >> 8]) : E;
    int deg = e2 - b;

    const unsigned char* hbase = Hh8 + lane * 4;
    float a0 = 0.f, a1 = 0.f, a2 = 0.f, a3 = 0.f;
    float p0 = 0.f, p1 = 0.f, p2 = 0.f, p3 = 0.f;

    for (int i0 = 0; i0 < deg; i0 += 64) {
        int j = i0 + lane;
        uint4 es = make_uint4(0u, 0u, 0u, 0u);
        if (j < deg) es = es_sorted[b + j];
        p0 += bf2f((unsigned short)(es.y & 0xffff));
        p1 += bf2f((unsigned short)(es.y >> 16));
        p2 += bf2f((unsigned short)(es.z & 0xffff));
        p3 += bf2f((unsigned short)(es.z >> 16));
        int cl = deg - i0; if (cl > 64) cl = 64;
        int jj = 0;
        for (; jj + 1 < cl; jj += 2) {
            unsigned uA   = (unsigned)__builtin_amdgcn_readlane((int)es.x, jj);
            unsigned sA01 = (unsigned)__builtin_amdgcn_readlane((int)es.y, jj);
            unsigned sA23 = (unsigned)__builtin_amdgcn_readlane((int)es.z, jj);
            unsigned uB   = (unsigned)__builtin_amdgcn_readlane((int)es.x, jj + 1);
            unsigned sB01 = (unsigned)__builtin_amdgcn_readlane((int)es.y, jj + 1);
            unsigned sB23 = (unsigned)__builtin_amdgcn_readlane((int)es.z, jj + 1);
            unsigned hvA = *(const unsigned*)(hbase + uA);
            unsigned hvB = *(const unsigned*)(hbase + uB);
            f32x2 loA = __builtin_amdgcn_cvt_pk_f32_fp8(hvA, false);
            f32x2 hiA = __builtin_amdgcn_cvt_pk_f32_fp8(hvA, true);
            f32x2 loB = __builtin_amdgcn_cvt_pk_f32_fp8(hvB, false);
            f32x2 hiB = __builtin_amdgcn_cvt_pk_f32_fp8(hvB, true);
            a0 += bf2f((unsigned short)(sA01 & 0xffff)) * loA.x;
            a1 += bf2f((unsigned short)(sA01 >> 16))    * loA.y;
            a2 += bf2f((unsigned short)(sA23 & 0xffff)) * hiA.x;
            a3 += bf2f((unsigned short)(sA23 >> 16))    * hiA.y;
            a0 += bf2f((unsigned short)(sB01 & 0xffff)) * loB.x;
            a1 += bf2f((unsigned short)(sB01 >> 16))    * loB.y;
            a2 += bf2f((unsigned short)(sB23 & 0xffff)) * hiB.x;
            a3 += bf2f((unsigned short)(sB23 >> 16))    * hiB.y;
        }
        if (jj < cl) {
            unsigned uA   = (unsigned)__builtin_amdgcn_readlane((int)es.x, jj);
            unsigned sA01 = (unsigned)__builtin_amdgcn_readlane((int)es.y, jj);
            unsigned sA23 = (unsigned)__builtin_amdgcn_readlane((int)es.z, jj);
            unsigned hvA = *(const unsigned*)(hbase + uA);
            f32x2 loA = __builtin_amdgcn_cvt_pk_f32_fp8(hvA, false);
            f32x2 hiA = __builtin_amdgcn_cvt_pk_f32_fp8(hvA, true);
            a0 += bf2f((unsigned short)(sA01 & 0xffff)) * loA.x;
            a1 += bf2f((unsigned short)(sA01 >> 16))    * loA.y;
            a2 += bf2f((unsigned short)(sA23 & 0xffff)) * hiA.x;
            a3 += bf2f((unsigned short)(sA23 >> 16))    * hiA.y;
        }
    }
#pragma unroll
    for (int off = 1; off < 64; off <<= 1) {
        p0 += __shfl_xor(p0, off); p1 += __shfl_xor(p1, off);
        p2 += __shfl_xor(p2, off); p3 += __shfl_xor(p3, off);
    }
    float r0 = 1.f / (p0 + 1e-16f), r1 = 1.f / (p1 + 1e-16f);
    float r2 = 1.f / (p2 + 1e-16f), r3 = 1.f / (p3 + 1e-16f);

    unsigned hr = *(const unsigned*)(Hr8 + ((size_t)v << 8) + lane * 4);
    f32x2 rlo = __builtin_amdgcn_cvt_pk_f32_fp8(hr, false);
    f32x2 rhi = __builtin_amdgcn_cvt_pk_f32_fp8(hr, true);
    float resv = bf2f(Rres[(size_t)v * OUTD + lane]);
    float yv = conv_b[0] + (resv > 0.f ? resv : 0.f);
    float tt;
    tt = a0 * r0 + rlo.x; tt = tt > 0.f ? tt : 0.f; yv += conv_w[0] * tt;
    tt = a1 * r1 + rlo.y; tt = tt > 0.f ? tt : 0.f; yv += conv_w[1] * tt;
    tt = a2 * r2 + rhi.x; tt = tt > 0.f ? tt : 0.f; yv += conv_w[2] * tt;
    tt = a3 * r3 + rhi.y; tt = tt > 0.f ? tt : 0.f; yv += conv_w[3] * tt;
    y[(size_t)v * OUTD + lane] = yv;
}

// ============ BN tail ============
__global__ __launch_bounds__(256) void bn_partial_kernel(const float* __restrict__ y,
                                                         float* __restrict__ bnsum,
                                                         float* __restrict__ bnsumsq, int total) {
    __shared__ float smem[256];
    int t = threadIdx.x;
    size_t idx = (size_t)blockIdx.x * 256 + t;
    size_t stride = (size_t)gridDim.x * 256;
    float sum = 0.f, sq = 0.f;
    for (; idx < (size_t)total; idx += stride) {
        float v = y[idx];
        sum += v; sq += v * v;
    }
    int d = t & 63;
    smem[t] = sum; __syncthreads();
    if (t < 64) atomicAdd(bnsum + d, smem[t] + smem[t + 64] + smem[t + 128] + smem[t + 192]);
    __syncthreads();
    smem[t] = sq; __syncthreads();
    if (t < 64) atomicAdd(bnsumsq + d, smem[t] + smem[t + 64] + smem[t + 128] + smem[t + 192]);
}

__global__ void norm_kernel(const float* __restrict__ y,
                            const float* __restrict__ bnsum, const float* __restrict__ bnsumsq,
                            const float* __restrict__ gamma, const float* __restrict__ beta,
                            float* __restrict__ out, int total4, float invN) {
    int idx = blockIdx.x * blockDim.x + threadIdx.x;
    if (idx >= total4) return;
    float4 v = *(const float4*)(y + (size_t)idx * 4);
    int d = (idx * 4) & 63;
    float4 o;
#pragma unroll
    for (int k = 0; k < 4; ++k) {
        float mean = bnsum[d + k] * invN;
        float var = bnsumsq[d + k] * invN - mean * mean;
        float sc = gamma[d + k] * rsqrtf(var + BN_EPS);
        float sh = beta[d + k] - mean * sc;
        (&o.x)[k] = (&v.x)[k] * sc + sh;
    }
    *(float4*)(out + (size_t)idx * 4) = o;
}

// ============ launch ============
extern "C" void kernel_launch(void* const* d_in, const int* in_sizes, int n_in,
                              void* d_out, int out_size, void* d_ws, size_t ws_size,
                              hipStream_t stream) {
    const float* node_feats = (const float*)d_in[0];
    const float* W_fc       = (const float*)d_in[1];
    const float* attn_l     = (const float*)d_in[2];
    const float* attn_r     = (const float*)d_in[3];
    const float* gat_res_w  = (const float*)d_in[4];
    const float* gat_bias   = (const float*)d_in[5];
    const float* conv_w     = (const float*)d_in[6];
    const float* conv_b     = (const float*)d_in[7];
    const float* res_w      = (const float*)d_in[8];
    const float* res_b      = (const float*)d_in[9];
    const float* bn_gamma   = (const float*)d_in[10];
    const float* bn_beta    = (const float*)d_in[11];
    const int*   src        = (const int*)d_in[12];
    const int*   dst        = (const int*)d_in[13];

    const int N = in_sizes[0] / IN_F;
    const int E = in_sizes[12];
    const int nb = (N + 255) / 256;

    char* ws = (char*)d_ws;
    size_t off = 0;
    auto alloc = [&](size_t bytes) -> void* {
        void* p = (void*)(ws + off);
        off += (bytes + 255) & ~(size_t)255;
        return p;
    };

    // --- zero zone ---
    int*   degree  = (int*)alloc((size_t)N * 4);
    float* bnsum   = (float*)alloc(64 * 4);
    float* bnsumsq = (float*)alloc(64 * 4);
    size_t zero_bytes = off;
    // --- rest ---
    int*            rank      = (int*)alloc((size_t)E * 4);
    int*            excl      = (int*)alloc((size_t)N * 4);
    int*            blocksum  = (int*)alloc(256 * 4);
    int*            base      = (int*)alloc(256 * 4);
    uint4*          es_sorted = (uint4*)alloc((size_t)E * 16);
    unsigned short* Btg2      = (unsigned short*)alloc((size_t)NCOLS * IN_F * 2);
    unsigned char*  Hh8       = (unsigned char*)alloc((size_t)N * 256);
    unsigned char*  Hr8       = (unsigned char*)alloc((size_t)N * 256);
    unsigned short* Rres      = (unsigned short*)alloc((size_t)N * OUTD * 2);
    float*          el        = (float*)alloc((size_t)N * 4 * 4);
    float*          er        = (float*)alloc((size_t)N * 4 * 4);
    float*          y         = (float*)alloc((size_t)N * OUTD * 4);
    (void)ws_size; (void)n_in; (void)out_size;

    hipMemsetAsync(d_ws, 0, zero_bytes, stream);

    // 0. pack B weights into fragment-ordered layout (+ folded attention vectors)
    k0_pack<<<289, 256, 0, stream>>>(W_fc, gat_res_w, res_w, attn_l, attn_r, Btg2);
    // 1. LDS-free MFMA GEMM + el/er + histogram
    k1_gemm<<<K1_BLOCKS, 256, 0, stream>>>(node_feats, Btg2, gat_bias, res_b,
                                           dst, degree, rank, Hh8, Hr8, Rres,
                                           el, er, N, E);
    // 2. scan
    scanA_kernel<<<nb, 256, 0, stream>>>(degree, excl, blocksum, N);
    scanB_kernel<<<1, 256, 0, stream>>>(blocksum, base, nb);
    // 3. scatter + score compute
    scatter_kernel<<<(E + 255) / 256, 256, 0, stream>>>(src, dst, rank, excl, base,
                                                        el, er, es_sorted, E);
    // 4. aggregation + epilogue
    agg_kernel<<<(N + 3) / 4, 256, 0, stream>>>(Hh8, Hr8, Rres, excl, base, es_sorted,
                                                conv_w, conv_b, y, N, E);
    // 5. BN
    bn_partial_kernel<<<512, 256, 0, stream>>>(y, bnsum, bnsumsq, N * OUTD);
    norm_kernel<<<(N * OUTD / 4 + 255) / 256, 256, 0, stream>>>(y, bnsum, bnsumsq,
                                                                bn_gamma, bn_beta, (float*)d_out,
                                                                N * OUTD / 4, 1.f / (float)N);
}